// Round 6
// baseline (425.330 us; speedup 1.0000x reference)
//
#include <hip/hip_runtime.h>
#include <hip/hip_bf16.h>

#define NB 32
#define NN 1024
#define IND 128
#define HD 64

typedef float f32x4 __attribute__((ext_vector_type(4)));
typedef short bf16x8 __attribute__((ext_vector_type(8)));
typedef unsigned short ushortx4 __attribute__((ext_vector_type(4)));

union FragU { unsigned short us[8]; bf16x8 v; };

__device__ __forceinline__ unsigned short f2bf(float f) {
    union { float f; unsigned u; } x; x.f = f;
    unsigned r = x.u + 0x7FFFu + ((x.u >> 16) & 1u);  // RNE
    return (unsigned short)(r >> 16);
}
__device__ __forceinline__ float bf2f(unsigned short h) {
    union { unsigned u; float f; } x; x.u = ((unsigned)h) << 16; return x.f;
}

// async 16B global -> LDS (DMA, no VGPR dest; counted by vmcnt)
__device__ __forceinline__ void gl16(void* lds, const void* g) {
    __builtin_amdgcn_global_load_lds(
        (const __attribute__((address_space(1))) unsigned int*)g,
        (__attribute__((address_space(3))) unsigned int*)lds, 16, 0, 0);
}

#define WAITVM(N) asm volatile("s_waitcnt vmcnt(" #N ")" ::: "memory")

// ---------------- kernel 0: weight prep (transpose + hi/lo bf16 split) ------
__global__ void prep_k(const float* __restrict__ W_h, const float* __restrict__ W_fc1,
                       const float* __restrict__ W_g1, const float* __restrict__ W_g2,
                       const float* __restrict__ b_g1, const float* __restrict__ b_g2,
                       unsigned short* __restrict__ WcT_hi, unsigned short* __restrict__ WcT_lo,
                       unsigned short* __restrict__ Wg1T_hi, unsigned short* __restrict__ Wg1T_lo,
                       unsigned short* __restrict__ Wg2T_hi, unsigned short* __restrict__ Wg2T_lo,
                       float* __restrict__ biasP1) {
    int t = blockIdx.x * blockDim.x + threadIdx.x;
    if (t < 16384) {
        int o = t >> 7, k = t & 127;
        float v = (o < 64) ? W_h[k * 64 + o] : W_fc1[k * 64 + (o - 64)];
        unsigned short hi = f2bf(v);
        WcT_hi[t] = hi; WcT_lo[t] = f2bf(v - bf2f(hi));
    } else if (t < 20480) {
        int r = t - 16384; int o = r >> 6, k = r & 63;
        float v = W_g1[k * 64 + o];
        unsigned short hi = f2bf(v);
        Wg1T_hi[r] = hi; Wg1T_lo[r] = f2bf(v - bf2f(hi));
    } else if (t < 24576) {
        int r = t - 20480; int o = r >> 6, k = r & 63;
        float v = W_g2[k * 64 + o];
        unsigned short hi = f2bf(v);
        Wg2T_hi[r] = hi; Wg2T_lo[r] = f2bf(v - bf2f(hi));
    } else if (t < 24640) {
        int j = t - 24576;
        biasP1[j] = b_g1[j] + b_g2[j];
    }
}

// ---------------- kernel 1: h (-> hF frag-major bf16), x_proj (f32), p1 -----
__global__ __launch_bounds__(64) void k1(
        const float* __restrict__ x,
        const unsigned short* __restrict__ WcT_hi, const unsigned short* __restrict__ WcT_lo,
        const unsigned short* __restrict__ Wg1T_hi, const unsigned short* __restrict__ Wg1T_lo,
        const float* __restrict__ b_h, const float* __restrict__ b_fc1,
        const float* __restrict__ biasP1,
        unsigned short* __restrict__ hF, float* __restrict__ xproj,
        float* __restrict__ p1) {
    __shared__ unsigned short lds_hi[16 * 64];
    __shared__ unsigned short lds_lo[16 * 64];

    const int lane = threadIdx.x;
    const int lr = lane & 15, lg = lane >> 4;
    const int blk = blockIdx.x;
    const int b = blk >> 6;
    const int n0 = (blk & 63) * 16;

    const float* xp = x + (size_t)(b * NN + n0 + lr) * IND;

    f32x4 xa[4][2];
#pragma unroll
    for (int ks = 0; ks < 4; ks++) {
        const f32x4* ap = (const f32x4*)(xp + 32 * ks + 8 * lg);
        xa[ks][0] = ap[0]; xa[ks][1] = ap[1];
    }

    f32x4 acc[8];
#pragma unroll
    for (int f = 0; f < 8; f++) acc[f] = (f32x4){0.f, 0.f, 0.f, 0.f};

#pragma unroll
    for (int ks = 0; ks < 4; ks++) {
        FragU ah, al;
#pragma unroll
        for (int i = 0; i < 4; i++) {
            unsigned short h0 = f2bf(xa[ks][0][i]); ah.us[i] = h0;     al.us[i]     = f2bf(xa[ks][0][i] - bf2f(h0));
            unsigned short h1 = f2bf(xa[ks][1][i]); ah.us[4 + i] = h1; al.us[4 + i] = f2bf(xa[ks][1][i] - bf2f(h1));
        }
#pragma unroll
        for (int f = 0; f < 8; f++) {
            int off = (16 * f + lr) * 128 + 32 * ks + 8 * lg;
            bf16x8 wh = *(const bf16x8*)(WcT_hi + off);
            bf16x8 wl = *(const bf16x8*)(WcT_lo + off);
            acc[f] = __builtin_amdgcn_mfma_f32_16x16x32_bf16(ah.v, wh, acc[f], 0, 0, 0);
            acc[f] = __builtin_amdgcn_mfma_f32_16x16x32_bf16(ah.v, wl, acc[f], 0, 0, 0);
            acc[f] = __builtin_amdgcn_mfma_f32_16x16x32_bf16(al.v, wh, acc[f], 0, 0, 0);
        }
    }

    const int mb = n0 + 4 * lg;
    const int tile = mb >> 5;
    const int lanepart = lr + 16 * ((mb >> 3) & 3);
    const int j0 = mb & 7;

#pragma unroll
    for (int f = 0; f < 4; f++) {
        int c = 16 * f + lr;
        float bh = b_h[c];
        ushortx4 hv;
#pragma unroll
        for (int r = 0; r < 4; r++) hv[r] = f2bf(acc[f][r] + bh);
        *(ushortx4*)(hF + (size_t)b * 65536 + (size_t)(tile * 4 + f) * 512 + lanepart * 8 + j0) = hv;
    }

#pragma unroll
    for (int f = 4; f < 8; f++) {
        int c = 16 * (f - 4) + lr;
        float bp = b_fc1[c];
#pragma unroll
        for (int r = 0; r < 4; r++) {
            float v = acc[f][r] + bp;
            int n = mb + r;
            xproj[(size_t)(b * NN + n) * 64 + c] = v;
            int ln = 4 * lg + r;
            int idx = ln * 64 + (((c >> 3) ^ (ln & 7)) << 3) + (c & 7);
            unsigned short hi = f2bf(v);
            lds_hi[idx] = hi;
            lds_lo[idx] = f2bf(v - bf2f(hi));
        }
    }
    __syncthreads();

    f32x4 accP[4];
#pragma unroll
    for (int f = 0; f < 4; f++) accP[f] = (f32x4){0.f, 0.f, 0.f, 0.f};
#pragma unroll
    for (int ks = 0; ks < 2; ks++) {
        int c0 = 32 * ks + 8 * lg;
        int idx = lr * 64 + (((c0 >> 3) ^ (lr & 7)) << 3);
        bf16x8 a_hi = *(const bf16x8*)(lds_hi + idx);
        bf16x8 a_lo = *(const bf16x8*)(lds_lo + idx);
#pragma unroll
        for (int f = 0; f < 4; f++) {
            int off = (16 * f + lr) * 64 + c0;
            bf16x8 b_hi = *(const bf16x8*)(Wg1T_hi + off);
            bf16x8 b_lo = *(const bf16x8*)(Wg1T_lo + off);
            accP[f] = __builtin_amdgcn_mfma_f32_16x16x32_bf16(a_hi, b_hi, accP[f], 0, 0, 0);
            accP[f] = __builtin_amdgcn_mfma_f32_16x16x32_bf16(a_hi, b_lo, accP[f], 0, 0, 0);
            accP[f] = __builtin_amdgcn_mfma_f32_16x16x32_bf16(a_lo, b_hi, accP[f], 0, 0, 0);
        }
    }
#pragma unroll
    for (int f = 0; f < 4; f++) {
        int c = 16 * f + lr;
        float bb = biasP1[c];
#pragma unroll
        for (int r = 0; r < 4; r++) {
            int n = mb + r;
            p1[(size_t)(b * NN + n) * 64 + c] = accP[f][r] + bb;
        }
    }
}

// ---------------- kernel 2: x_new = A@h via LDS pipeline; fused epilogue ----
// (byte-identical to round 5 — frozen baseline)
__global__ __launch_bounds__(256, 2) void k2(
        const float* __restrict__ A, const unsigned short* __restrict__ hF,
        const unsigned short* __restrict__ Wg2T_hi, const unsigned short* __restrict__ Wg2T_lo,
        const float* __restrict__ p1, const float* __restrict__ xproj,
        float* __restrict__ out) {
    __shared__ char smem[73728];

    const int tid = threadIdx.x;
    const int w = tid >> 6, lane = tid & 63;
    const int lr = lane & 15, lg = lane >> 4;
    const int b = blockIdx.x >> 4;
    const int rt = blockIdx.x & 15;

    const float* aS[4];
#pragma unroll
    for (int i = 0; i < 4; i++) {
        int rowl = w * 16 + i * 4 + lg;
        int g = (lane & 15) ^ ((i * 4 + lg) & 15);
        aS[i] = A + (size_t)(b * NN + rt * 64 + rowl) * NN + g * 4;
    }
    const unsigned short* hS[2];
#pragma unroll
    for (int j = 0; j < 2; j++)
        hS[j] = hF + (size_t)b * 65536 + (w * 2 + j) * 512 + lane * 8;

#define STAGE(T, SLOT)                                                        \
    {                                                                         \
        _Pragma("unroll")                                                     \
        for (int i = 0; i < 4; i++)                                           \
            gl16(smem + (SLOT) * 16384 + (w * 4 + i) * 1024, aS[i] + (T) * 64); \
        _Pragma("unroll")                                                     \
        for (int j = 0; j < 2; j++)                                           \
            gl16(smem + 49152 + (SLOT) * 8192 + (w * 2 + j) * 1024, hS[j] + (T) * 4096); \
    }

    f32x4 acc[4];
#pragma unroll
    for (int f = 0; f < 4; f++) acc[f] = (f32x4){0.f, 0.f, 0.f, 0.f};

    STAGE(0, 0) STAGE(1, 1) STAGE(2, 2)

    const char* Arow = smem + (w * 16 + lr) * 256;

#pragma unroll
    for (int t = 0; t < 16; ++t) {
        const int slot = t % 3;
        if (t < 14)      { WAITVM(12); }
        else if (t == 14){ WAITVM(6);  }
        else             { WAITVM(0);  }
        __builtin_amdgcn_s_barrier();
        __builtin_amdgcn_sched_barrier(0);

#pragma unroll
        for (int kc = 0; kc < 2; kc++) {
            int g0 = kc * 8 + 2 * lg;
            f32x4 a0 = *(const f32x4*)(Arow + slot * 16384 + ((g0 ^ lr) << 4));
            f32x4 a1 = *(const f32x4*)(Arow + slot * 16384 + (((g0 + 1) ^ lr) << 4));
            FragU au;
#pragma unroll
            for (int i = 0; i < 4; i++) { au.us[i] = f2bf(a0[i]); au.us[4 + i] = f2bf(a1[i]); }
            const char* Hb = smem + 49152 + slot * 8192 + kc * 4096 + lane * 16;
#pragma unroll
            for (int f = 0; f < 4; f++) {
                bf16x8 hfv = *(const bf16x8*)(Hb + f * 1024);
                acc[f] = __builtin_amdgcn_mfma_f32_16x16x32_bf16(au.v, hfv, acc[f], 0, 0, 0);
            }
        }

        asm volatile("s_waitcnt lgkmcnt(0)" ::: "memory");
        __builtin_amdgcn_sched_barrier(0);
        __builtin_amdgcn_s_barrier();
        if (t + 3 < 16) STAGE(t + 3, slot)
    }

    unsigned short* th = (unsigned short*)(smem + w * 4096);
    unsigned short* tl = th + 1024;
#pragma unroll
    for (int f = 0; f < 4; f++) {
        int c = 16 * f + lr;
#pragma unroll
        for (int r = 0; r < 4; r++) {
            int row = 4 * lg + r;
            int idx = row * 64 + (((c >> 3) ^ (row & 7)) << 3) + (c & 7);
            float v = acc[f][r];
            unsigned short hi = f2bf(v);
            th[idx] = hi;
            tl[idx] = f2bf(v - bf2f(hi));
        }
    }
    asm volatile("s_waitcnt lgkmcnt(0)" ::: "memory");

    f32x4 accG[4];
#pragma unroll
    for (int f = 0; f < 4; f++) accG[f] = (f32x4){0.f, 0.f, 0.f, 0.f};
#pragma unroll
    for (int ks = 0; ks < 2; ks++) {
        int c0k = 32 * ks + 8 * lg;
        int idx = lr * 64 + (((c0k >> 3) ^ (lr & 7)) << 3);
        bf16x8 a_hi = *(const bf16x8*)(th + idx);
        bf16x8 a_lo = *(const bf16x8*)(tl + idx);
#pragma unroll
        for (int f = 0; f < 4; f++) {
            int off = (16 * f + lr) * 64 + c0k;
            bf16x8 b_hi = *(const bf16x8*)(Wg2T_hi + off);
            bf16x8 b_lo = *(const bf16x8*)(Wg2T_lo + off);
            accG[f] = __builtin_amdgcn_mfma_f32_16x16x32_bf16(a_hi, b_hi, accG[f], 0, 0, 0);
            accG[f] = __builtin_amdgcn_mfma_f32_16x16x32_bf16(a_hi, b_lo, accG[f], 0, 0, 0);
            accG[f] = __builtin_amdgcn_mfma_f32_16x16x32_bf16(a_lo, b_hi, accG[f], 0, 0, 0);
        }
    }

    const int n0w = rt * 64 + w * 16;
#pragma unroll
    for (int f = 0; f < 4; f++) {
        int c = 16 * f + lr;
#pragma unroll
        for (int r = 0; r < 4; r++) {
            int n = n0w + 4 * lg + r;
            size_t g = (size_t)(b * NN + n) * 64 + c;
            float z = p1[g] + accG[f][r];
            float gate = 1.f / (1.f + __expf(-z));
            float xpv = xproj[g];
            out[g] = acc[f][r] * gate + xpv * (1.f - gate);
        }
    }
#undef STAGE
}

// ================= DIAGNOSTIC PROBES (outputs go to scratch only) ===========

// probe_ideal: grid-stride float4 read of A, 4 passes (~536 MB)
__global__ __launch_bounds__(256) void probe_ideal(const float* __restrict__ A,
                                                   float* __restrict__ sink) {
    const size_t nt = (size_t)gridDim.x * 256;
    const size_t tid = (size_t)blockIdx.x * 256 + threadIdx.x;
    f32x4 s = (f32x4){0.f, 0.f, 0.f, 0.f};
    for (int rep = 0; rep < 4; rep++) {
        for (size_t i = tid; i < (size_t)NB * NN * NN / 4; i += nt) {
            f32x4 v = ((const f32x4*)A)[i];
            s += v;
        }
    }
    sink[tid] = s[0] + s[1] + s[2] + s[3];
}

// shared staging helper for the probes (identical geometry to k2)
#define PROBE_SETUP                                                            \
    const int tid = threadIdx.x;                                               \
    const int w = tid >> 6, lane = tid & 63;                                   \
    const int lg = lane >> 4;                                                  \
    const int b = blockIdx.x >> 4;                                             \
    const int rt = blockIdx.x & 15;                                            \
    const float* aS[4];                                                        \
    _Pragma("unroll")                                                          \
    for (int i = 0; i < 4; i++) {                                              \
        int rowl = w * 16 + i * 4 + lg;                                        \
        int g = (lane & 15) ^ ((i * 4 + lg) & 15);                             \
        aS[i] = A + (size_t)(b * NN + rt * 64 + rowl) * NN + g * 4;            \
    }                                                                          \
    const unsigned short* hS[2];                                               \
    _Pragma("unroll")                                                          \
    for (int j = 0; j < 2; j++)                                                \
        hS[j] = hF + (size_t)b * 65536 + (w * 2 + j) * 512 + lane * 8;

#define STAGE(T, SLOT)                                                         \
    {                                                                          \
        _Pragma("unroll")                                                      \
        for (int i = 0; i < 4; i++)                                            \
            gl16(smem + (SLOT) * 16384 + (w * 4 + i) * 1024, aS[i] + (T) * 64);\
        _Pragma("unroll")                                                      \
        for (int j = 0; j < 2; j++)                                            \
            gl16(smem + 49152 + (SLOT) * 8192 + (w * 2 + j) * 1024, hS[j] + (T) * 4096); \
    }

// probe_nowait: k2 staging geometry, free-running issue, 64 tiles (A x4)
__global__ __launch_bounds__(256, 2) void probe_nowait(const float* __restrict__ A,
                                                       const unsigned short* __restrict__ hF,
                                                       int* __restrict__ sink) {
    __shared__ char smem[73728];
    PROBE_SETUP
    for (int t = 0; t < 64; ++t) {
        STAGE((t & 15), (t % 3))
    }
    WAITVM(0);
    __syncthreads();
    sink[(size_t)blockIdx.x * 256 + tid] = ((const int*)smem)[tid];
}

// probe_stage: k2 staging with full vmcnt + double-barrier cadence, no compute
__global__ __launch_bounds__(256, 2) void probe_stage(const float* __restrict__ A,
                                                      const unsigned short* __restrict__ hF,
                                                      int* __restrict__ sink) {
    __shared__ char smem[73728];
    PROBE_SETUP
    STAGE(0, 0) STAGE(1, 1) STAGE(2, 2)
    for (int t = 0; t < 64; ++t) {
        const int slot = t % 3;
        if (t < 62)      { WAITVM(12); }
        else if (t == 62){ WAITVM(6);  }
        else             { WAITVM(0);  }
        __builtin_amdgcn_s_barrier();
        __builtin_amdgcn_sched_barrier(0);
        // (no compute)
        asm volatile("s_waitcnt lgkmcnt(0)" ::: "memory");
        __builtin_amdgcn_s_barrier();
        if (t + 3 < 64) STAGE(((t + 3) & 15), slot)
    }
    __syncthreads();
    sink[(size_t)blockIdx.x * 256 + tid] = ((const int*)smem)[tid];
}

// k2_probe: full k2 main loop x4 (staging + LDS reads + MFMA), sink output
__global__ __launch_bounds__(256, 2) void k2_probe(const float* __restrict__ A,
                                                   const unsigned short* __restrict__ hF,
                                                   float* __restrict__ sink) {
    __shared__ char smem[73728];
    PROBE_SETUP
    const int lr = lane & 15;

    f32x4 acc[4];
#pragma unroll
    for (int f = 0; f < 4; f++) acc[f] = (f32x4){0.f, 0.f, 0.f, 0.f};

    STAGE(0, 0) STAGE(1, 1) STAGE(2, 2)

    const char* Arow = smem + (w * 16 + lr) * 256;

    for (int t = 0; t < 64; ++t) {
        const int slot = t % 3;
        if (t < 62)      { WAITVM(12); }
        else if (t == 62){ WAITVM(6);  }
        else             { WAITVM(0);  }
        __builtin_amdgcn_s_barrier();
        __builtin_amdgcn_sched_barrier(0);

#pragma unroll
        for (int kc = 0; kc < 2; kc++) {
            int g0 = kc * 8 + 2 * lg;
            f32x4 a0 = *(const f32x4*)(Arow + slot * 16384 + ((g0 ^ lr) << 4));
            f32x4 a1 = *(const f32x4*)(Arow + slot * 16384 + (((g0 + 1) ^ lr) << 4));
            FragU au;
#pragma unroll
            for (int i = 0; i < 4; i++) { au.us[i] = f2bf(a0[i]); au.us[4 + i] = f2bf(a1[i]); }
            const char* Hb = smem + 49152 + slot * 8192 + kc * 4096 + lane * 16;
#pragma unroll
            for (int f = 0; f < 4; f++) {
                bf16x8 hfv = *(const bf16x8*)(Hb + f * 1024);
                acc[f] = __builtin_amdgcn_mfma_f32_16x16x32_bf16(au.v, hfv, acc[f], 0, 0, 0);
            }
        }

        asm volatile("s_waitcnt lgkmcnt(0)" ::: "memory");
        __builtin_amdgcn_sched_barrier(0);
        __builtin_amdgcn_s_barrier();
        if (t + 3 < 64) STAGE(((t + 3) & 15), slot)
    }

    float* sp = sink + ((size_t)blockIdx.x * 256 + tid) * 16;
#pragma unroll
    for (int f = 0; f < 4; f++) *(f32x4*)(sp + 4 * f) = acc[f];
}
#undef STAGE
#undef PROBE_SETUP

extern "C" void kernel_launch(void* const* d_in, const int* in_sizes, int n_in,
                              void* d_out, int out_size, void* d_ws, size_t ws_size,
                              hipStream_t stream) {
    const float* x     = (const float*)d_in[0];
    const float* A     = (const float*)d_in[1];
    const float* W_h   = (const float*)d_in[2];
    const float* b_h   = (const float*)d_in[3];
    const float* W_fc1 = (const float*)d_in[4];
    const float* b_fc1 = (const float*)d_in[5];
    const float* W_g1  = (const float*)d_in[6];
    const float* b_g1  = (const float*)d_in[7];
    const float* W_g2  = (const float*)d_in[8];
    const float* b_g2  = (const float*)d_in[9];
    float* out = (float*)d_out;

    char* ws = (char*)d_ws;
    unsigned short* WcT_hi  = (unsigned short*)(ws);
    unsigned short* WcT_lo  = (unsigned short*)(ws + 32768);
    unsigned short* Wg1T_hi = (unsigned short*)(ws + 65536);
    unsigned short* Wg1T_lo = (unsigned short*)(ws + 73728);
    unsigned short* Wg2T_hi = (unsigned short*)(ws + 81920);
    unsigned short* Wg2T_lo = (unsigned short*)(ws + 90112);
    float*          bP1     = (float*)(ws + 98304);
    unsigned short* hF      = (unsigned short*)(ws + 131072);                      // 4 MB
    float*          xprj    = (float*)(ws + 131072 + 4194304);                     // 8 MB
    float*          p1      = (float*)(ws + 131072 + 4194304 + 8388608);           // 8 MB
    // probe sinks
    float* sinkP  = (float*)(ws + (size_t)32 * 1024 * 1024);                       // 8 MB
    float* sinkI  = (float*)(ws + (size_t)42 * 1024 * 1024);                       // 2 MB
    int*   sinkS1 = (int*)  (ws + (size_t)45 * 1024 * 1024);                       // 512 KB
    int*   sinkS2 = (int*)  (ws + (size_t)46 * 1024 * 1024);                       // 512 KB

    prep_k<<<97, 256, 0, stream>>>(W_h, W_fc1, W_g1, W_g2, b_g1, b_g2,
                                   WcT_hi, WcT_lo, Wg1T_hi, Wg1T_lo, Wg2T_hi, Wg2T_lo, bP1);
    k1<<<2048, 64, 0, stream>>>(x, WcT_hi, WcT_lo, Wg1T_hi, Wg1T_lo, b_h, b_fc1, bP1,
                                hF, xprj, p1);
    k2<<<512, 256, 0, stream>>>(A, hF, Wg2T_hi, Wg2T_lo, p1, xprj, out);

    // diagnostics (scratch-only outputs; stream-serialized after real kernels)
    k2_probe   <<<512, 256, 0, stream>>>(A, hF, sinkP);
    probe_stage<<<512, 256, 0, stream>>>(A, hF, sinkS1);
    probe_nowait<<<512, 256, 0, stream>>>(A, hF, sinkS2);
    probe_ideal<<<2048, 256, 0, stream>>>(A, sinkI);
}

// Round 7
// 64.263 us; speedup vs baseline: 6.6186x; 6.6186x over previous
//
#include <hip/hip_runtime.h>
#include <hip/hip_bf16.h>

#define NB 32
#define NN 1024
#define IND 128
#define HD 64

typedef float f32x4 __attribute__((ext_vector_type(4)));
typedef short bf16x8 __attribute__((ext_vector_type(8)));
typedef unsigned short ushortx4 __attribute__((ext_vector_type(4)));

union FragU { unsigned short us[8]; bf16x8 v; };

__device__ __forceinline__ unsigned short f2bf(float f) {
    union { float f; unsigned u; } x; x.f = f;
    unsigned r = x.u + 0x7FFFu + ((x.u >> 16) & 1u);  // RNE
    return (unsigned short)(r >> 16);
}
__device__ __forceinline__ float bf2f(unsigned short h) {
    union { unsigned u; float f; } x; x.u = ((unsigned)h) << 16; return x.f;
}

// async 16B global -> LDS (DMA, no VGPR dest; counted by vmcnt)
__device__ __forceinline__ void gl16(void* lds, const void* g) {
    __builtin_amdgcn_global_load_lds(
        (const __attribute__((address_space(1))) unsigned int*)g,
        (__attribute__((address_space(3))) unsigned int*)lds, 16, 0, 0);
}

// ---------------- kernel 0: weight prep (transpose + hi/lo bf16 split) ------
__global__ void prep_k(const float* __restrict__ W_h, const float* __restrict__ W_fc1,
                       const float* __restrict__ W_g1, const float* __restrict__ W_g2,
                       const float* __restrict__ b_g1, const float* __restrict__ b_g2,
                       unsigned short* __restrict__ WcT_hi, unsigned short* __restrict__ WcT_lo,
                       unsigned short* __restrict__ Wg1T_hi, unsigned short* __restrict__ Wg1T_lo,
                       unsigned short* __restrict__ Wg2T_hi, unsigned short* __restrict__ Wg2T_lo,
                       float* __restrict__ biasP1) {
    int t = blockIdx.x * blockDim.x + threadIdx.x;
    if (t < 16384) {
        int o = t >> 7, k = t & 127;
        float v = (o < 64) ? W_h[k * 64 + o] : W_fc1[k * 64 + (o - 64)];
        unsigned short hi = f2bf(v);
        WcT_hi[t] = hi; WcT_lo[t] = f2bf(v - bf2f(hi));
    } else if (t < 20480) {
        int r = t - 16384; int o = r >> 6, k = r & 63;
        float v = W_g1[k * 64 + o];
        unsigned short hi = f2bf(v);
        Wg1T_hi[r] = hi; Wg1T_lo[r] = f2bf(v - bf2f(hi));
    } else if (t < 24576) {
        int r = t - 20480; int o = r >> 6, k = r & 63;
        float v = W_g2[k * 64 + o];
        unsigned short hi = f2bf(v);
        Wg2T_hi[r] = hi; Wg2T_lo[r] = f2bf(v - bf2f(hi));
    } else if (t < 24640) {
        int j = t - 24576;
        biasP1[j] = b_g1[j] + b_g2[j];
    }
}

// ---------------- kernel 1: h (-> hF frag-major bf16), x_proj (f32), p1 -----
// (unchanged from round 5)
__global__ __launch_bounds__(64) void k1(
        const float* __restrict__ x,
        const unsigned short* __restrict__ WcT_hi, const unsigned short* __restrict__ WcT_lo,
        const unsigned short* __restrict__ Wg1T_hi, const unsigned short* __restrict__ Wg1T_lo,
        const float* __restrict__ b_h, const float* __restrict__ b_fc1,
        const float* __restrict__ biasP1,
        unsigned short* __restrict__ hF, float* __restrict__ xproj,
        float* __restrict__ p1) {
    __shared__ unsigned short lds_hi[16 * 64];
    __shared__ unsigned short lds_lo[16 * 64];

    const int lane = threadIdx.x;
    const int lr = lane & 15, lg = lane >> 4;
    const int blk = blockIdx.x;
    const int b = blk >> 6;
    const int n0 = (blk & 63) * 16;

    const float* xp = x + (size_t)(b * NN + n0 + lr) * IND;

    f32x4 xa[4][2];
#pragma unroll
    for (int ks = 0; ks < 4; ks++) {
        const f32x4* ap = (const f32x4*)(xp + 32 * ks + 8 * lg);
        xa[ks][0] = ap[0]; xa[ks][1] = ap[1];
    }

    f32x4 acc[8];
#pragma unroll
    for (int f = 0; f < 8; f++) acc[f] = (f32x4){0.f, 0.f, 0.f, 0.f};

#pragma unroll
    for (int ks = 0; ks < 4; ks++) {
        FragU ah, al;
#pragma unroll
        for (int i = 0; i < 4; i++) {
            unsigned short h0 = f2bf(xa[ks][0][i]); ah.us[i] = h0;     al.us[i]     = f2bf(xa[ks][0][i] - bf2f(h0));
            unsigned short h1 = f2bf(xa[ks][1][i]); ah.us[4 + i] = h1; al.us[4 + i] = f2bf(xa[ks][1][i] - bf2f(h1));
        }
#pragma unroll
        for (int f = 0; f < 8; f++) {
            int off = (16 * f + lr) * 128 + 32 * ks + 8 * lg;
            bf16x8 wh = *(const bf16x8*)(WcT_hi + off);
            bf16x8 wl = *(const bf16x8*)(WcT_lo + off);
            acc[f] = __builtin_amdgcn_mfma_f32_16x16x32_bf16(ah.v, wh, acc[f], 0, 0, 0);
            acc[f] = __builtin_amdgcn_mfma_f32_16x16x32_bf16(ah.v, wl, acc[f], 0, 0, 0);
            acc[f] = __builtin_amdgcn_mfma_f32_16x16x32_bf16(al.v, wh, acc[f], 0, 0, 0);
        }
    }

    const int mb = n0 + 4 * lg;
    const int tile = mb >> 5;
    const int lanepart = lr + 16 * ((mb >> 3) & 3);
    const int j0 = mb & 7;

#pragma unroll
    for (int f = 0; f < 4; f++) {
        int c = 16 * f + lr;
        float bh = b_h[c];
        ushortx4 hv;
#pragma unroll
        for (int r = 0; r < 4; r++) hv[r] = f2bf(acc[f][r] + bh);
        *(ushortx4*)(hF + (size_t)b * 65536 + (size_t)(tile * 4 + f) * 512 + lanepart * 8 + j0) = hv;
    }

#pragma unroll
    for (int f = 4; f < 8; f++) {
        int c = 16 * (f - 4) + lr;
        float bp = b_fc1[c];
#pragma unroll
        for (int r = 0; r < 4; r++) {
            float v = acc[f][r] + bp;
            int n = mb + r;
            xproj[(size_t)(b * NN + n) * 64 + c] = v;
            int ln = 4 * lg + r;
            int idx = ln * 64 + (((c >> 3) ^ (ln & 7)) << 3) + (c & 7);
            unsigned short hi = f2bf(v);
            lds_hi[idx] = hi;
            lds_lo[idx] = f2bf(v - bf2f(hi));
        }
    }
    __syncthreads();

    f32x4 accP[4];
#pragma unroll
    for (int f = 0; f < 4; f++) accP[f] = (f32x4){0.f, 0.f, 0.f, 0.f};
#pragma unroll
    for (int ks = 0; ks < 2; ks++) {
        int c0 = 32 * ks + 8 * lg;
        int idx = lr * 64 + (((c0 >> 3) ^ (lr & 7)) << 3);
        bf16x8 a_hi = *(const bf16x8*)(lds_hi + idx);
        bf16x8 a_lo = *(const bf16x8*)(lds_lo + idx);
#pragma unroll
        for (int f = 0; f < 4; f++) {
            int off = (16 * f + lr) * 64 + c0;
            bf16x8 b_hi = *(const bf16x8*)(Wg1T_hi + off);
            bf16x8 b_lo = *(const bf16x8*)(Wg1T_lo + off);
            accP[f] = __builtin_amdgcn_mfma_f32_16x16x32_bf16(a_hi, b_hi, accP[f], 0, 0, 0);
            accP[f] = __builtin_amdgcn_mfma_f32_16x16x32_bf16(a_hi, b_lo, accP[f], 0, 0, 0);
            accP[f] = __builtin_amdgcn_mfma_f32_16x16x32_bf16(a_lo, b_hi, accP[f], 0, 0, 0);
        }
    }
#pragma unroll
    for (int f = 0; f < 4; f++) {
        int c = 16 * f + lr;
        float bb = biasP1[c];
#pragma unroll
        for (int r = 0; r < 4; r++) {
            int n = mb + r;
            p1[(size_t)(b * NN + n) * 64 + c] = accP[f][r] + bb;
        }
    }
}

// ---------------- kernel 2: x_new = A@h, BK=256 (1KB bursts); fused epilogue
// grid 1024 x 256; block = 32 rows x 64 cols of one batch; 4 K-tiles of 256.
// Wave (wr,wc) computes rows 16wr..+15, cols 32wc..+31 (2 frags).
// A staged via gl16: one instruction = 1 KB of ONE row (64 lanes x 16B),
// source granule pre-swizzled (g ^= row&63), read with same XOR ->
// conflict-free ds_read_b128. hF consumed into regs (1KB contiguous L2 loads).
__global__ __launch_bounds__(256, 2) void k2(
        const float* __restrict__ A, const unsigned short* __restrict__ hF,
        const unsigned short* __restrict__ Wg2T_hi, const unsigned short* __restrict__ Wg2T_lo,
        const float* __restrict__ p1, const float* __restrict__ xproj,
        float* __restrict__ out) {
    __shared__ char smem[65536];   // A: 2 slots x 32 KB

    const int tid = threadIdx.x;
    const int w = tid >> 6, lane = tid & 63;
    const int lr = lane & 15, lg = lane >> 4;
    const int wr = w >> 1, wc = w & 1;

    // XCD-bijective swizzle (1024 % 8 == 0): each XCD gets 4 whole batches
    const int wgid = ((int)blockIdx.x & 7) * 128 + ((int)blockIdx.x >> 3);
    const int b = wgid >> 5;
    const int rt = wgid & 31;

    // staging sources: wave w stages rows 8w..8w+7; instr i -> row 8w+i
    const float* aS[8];
#pragma unroll
    for (int i = 0; i < 8; i++) {
        int rl = w * 8 + i;
        aS[i] = A + (size_t)(b * NN + rt * 32 + rl) * NN + ((lane ^ rl) << 2);
    }
    const unsigned short* hBase = hF + (size_t)b * 65536;

    f32x4 acc[2];
    acc[0] = (f32x4){0.f, 0.f, 0.f, 0.f};
    acc[1] = (f32x4){0.f, 0.f, 0.f, 0.f};

    bf16x8 hb[8][2];

    // prologue: stage A(0) -> slot0; load hb(0)
#pragma unroll
    for (int i = 0; i < 8; i++)
        gl16(smem + (w * 8 + i) * 1024, aS[i]);
#pragma unroll
    for (int ks = 0; ks < 8; ks++)
#pragma unroll
        for (int i = 0; i < 2; i++)
            hb[ks][i] = *(const bf16x8*)(hBase + (size_t)(ks * 4 + 2 * wc + i) * 512 + lane * 8);
    __syncthreads();

    const int rl_c = 16 * wr + lr;   // this lane's compute row (0..31)

#define COMPUTE(ks, Abase)                                                     \
    {                                                                          \
        int g0 = (ks) * 8 + lg * 2;                                            \
        f32x4 a0 = *(const f32x4*)((Abase) + ((g0 ^ rl_c) << 4));              \
        f32x4 a1 = *(const f32x4*)((Abase) + (((g0 + 1) ^ rl_c) << 4));        \
        FragU au;                                                              \
        _Pragma("unroll")                                                      \
        for (int ii = 0; ii < 4; ii++) {                                       \
            au.us[ii] = f2bf(a0[ii]); au.us[4 + ii] = f2bf(a1[ii]);            \
        }                                                                      \
        acc[0] = __builtin_amdgcn_mfma_f32_16x16x32_bf16(au.v, hb[ks][0], acc[0], 0, 0, 0); \
        acc[1] = __builtin_amdgcn_mfma_f32_16x16x32_bf16(au.v, hb[ks][1], acc[1], 0, 0, 0); \
    }

#pragma unroll
    for (int t = 0; t < 4; t++) {
        const int slot = t & 1;
        const char* Abase = smem + slot * 32768 + rl_c * 1024;

        // stage next A-tile into other slot (HBM latency hides under compute)
        if (t < 3) {
#pragma unroll
            for (int i = 0; i < 8; i++)
                gl16(smem + (slot ^ 1) * 32768 + (w * 8 + i) * 1024,
                     aS[i] + (t + 1) * 256);
        }

        COMPUTE(0, Abase) COMPUTE(1, Abase) COMPUTE(2, Abase) COMPUTE(3, Abase)
        if (t < 3) {   // reload first half of hb for t+1 (regs just freed)
#pragma unroll
            for (int ks = 0; ks < 4; ks++)
#pragma unroll
                for (int i = 0; i < 2; i++)
                    hb[ks][i] = *(const bf16x8*)(hBase +
                        (size_t)(((t + 1) * 8 + ks) * 4 + 2 * wc + i) * 512 + lane * 8);
        }
        COMPUTE(4, Abase) COMPUTE(5, Abase) COMPUTE(6, Abase) COMPUTE(7, Abase)
        if (t < 3) {   // reload second half
#pragma unroll
            for (int ks = 4; ks < 8; ks++)
#pragma unroll
                for (int i = 0; i < 2; i++)
                    hb[ks][i] = *(const bf16x8*)(hBase +
                        (size_t)(((t + 1) * 8 + ks) * 4 + 2 * wc + i) * 512 + lane * 8);
        }
        __syncthreads();   // drains vmcnt(0): A(t+1) + hb(t+1) complete
    }
#undef COMPUTE

    // ---- epilogue: xnew tiles (per row-strip wr, shared by wc waves) ----
    unsigned short* th = (unsigned short*)(smem + wr * 4096);
    unsigned short* tl = th + 1024;
#pragma unroll
    for (int i = 0; i < 2; i++) {
        int c = 32 * wc + 16 * i + lr;
#pragma unroll
        for (int r = 0; r < 4; r++) {
            int ln = 4 * lg + r;
            int idx = ln * 64 + (((c >> 3) ^ (ln & 7)) << 3) + (c & 7);
            float v = acc[i][r];
            unsigned short hi = f2bf(v);
            th[idx] = hi;
            tl[idx] = f2bf(v - bf2f(hi));
        }
    }
    __syncthreads();

    // g2 = x_new @ W_g2 (split precision); wave computes its 2 col-frags
    f32x4 accG[2];
    accG[0] = (f32x4){0.f, 0.f, 0.f, 0.f};
    accG[1] = (f32x4){0.f, 0.f, 0.f, 0.f};
#pragma unroll
    for (int ksk = 0; ksk < 2; ksk++) {
        int c0k = 32 * ksk + 8 * lg;
        int idx = lr * 64 + (((c0k >> 3) ^ (lr & 7)) << 3);
        bf16x8 a_hi = *(const bf16x8*)(th + idx);
        bf16x8 a_lo = *(const bf16x8*)(tl + idx);
#pragma unroll
        for (int i = 0; i < 2; i++) {
            int off = (16 * (2 * wc + i) + lr) * 64 + c0k;
            bf16x8 b_hi = *(const bf16x8*)(Wg2T_hi + off);
            bf16x8 b_lo = *(const bf16x8*)(Wg2T_lo + off);
            accG[i] = __builtin_amdgcn_mfma_f32_16x16x32_bf16(a_hi, b_hi, accG[i], 0, 0, 0);
            accG[i] = __builtin_amdgcn_mfma_f32_16x16x32_bf16(a_hi, b_lo, accG[i], 0, 0, 0);
            accG[i] = __builtin_amdgcn_mfma_f32_16x16x32_bf16(a_lo, b_hi, accG[i], 0, 0, 0);
        }
    }

    // fused epilogue: gate = sigmoid(p1 + g2); out = xnew*g + xproj*(1-g)
#pragma unroll
    for (int i = 0; i < 2; i++) {
        int c = 16 * (2 * wc + i) + lr;
#pragma unroll
        for (int r = 0; r < 4; r++) {
            int n = rt * 32 + 16 * wr + 4 * lg + r;
            size_t g = (size_t)(b * NN + n) * 64 + c;
            float z = p1[g] + accG[i][r];
            float gate = 1.f / (1.f + __expf(-z));
            float xpv = xproj[g];
            out[g] = acc[i][r] * gate + xpv * (1.f - gate);
        }
    }
}

extern "C" void kernel_launch(void* const* d_in, const int* in_sizes, int n_in,
                              void* d_out, int out_size, void* d_ws, size_t ws_size,
                              hipStream_t stream) {
    const float* x     = (const float*)d_in[0];
    const float* A     = (const float*)d_in[1];
    const float* W_h   = (const float*)d_in[2];
    const float* b_h   = (const float*)d_in[3];
    const float* W_fc1 = (const float*)d_in[4];
    const float* b_fc1 = (const float*)d_in[5];
    const float* W_g1  = (const float*)d_in[6];
    const float* b_g1  = (const float*)d_in[7];
    const float* W_g2  = (const float*)d_in[8];
    const float* b_g2  = (const float*)d_in[9];
    float* out = (float*)d_out;

    char* ws = (char*)d_ws;
    unsigned short* WcT_hi  = (unsigned short*)(ws);            // 32 KB
    unsigned short* WcT_lo  = (unsigned short*)(ws + 32768);    // 32 KB
    unsigned short* Wg1T_hi = (unsigned short*)(ws + 65536);    // 8 KB
    unsigned short* Wg1T_lo = (unsigned short*)(ws + 73728);    // 8 KB
    unsigned short* Wg2T_hi = (unsigned short*)(ws + 81920);    // 8 KB
    unsigned short* Wg2T_lo = (unsigned short*)(ws + 90112);    // 8 KB
    float*          bP1     = (float*)(ws + 98304);             // 256 B
    unsigned short* hF      = (unsigned short*)(ws + 131072);                      // 4 MB
    float*          xprj    = (float*)(ws + 131072 + 4194304);                     // 8 MB
    float*          p1      = (float*)(ws + 131072 + 4194304 + 8388608);           // 8 MB

    prep_k<<<97, 256, 0, stream>>>(W_h, W_fc1, W_g1, W_g2, b_g1, b_g2,
                                   WcT_hi, WcT_lo, Wg1T_hi, Wg1T_lo, Wg2T_hi, Wg2T_lo, bP1);
    k1<<<2048, 64, 0, stream>>>(x, WcT_hi, WcT_lo, Wg1T_hi, Wg1T_lo, b_h, b_fc1, bP1,
                                hF, xprj, p1);
    k2<<<1024, 256, 0, stream>>>(A, hF, Wg2T_hi, Wg2T_lo, p1, xprj, out);
}